// Round 4
// baseline (1636.190 us; speedup 1.0000x reference)
//
#include <hip/hip_runtime.h>

// SGM min-sum message passing, 4 directions, dense 21x21 label context.
// out = sum_d L_d - 3u.
//
// Path A (ws >= ~399 MB):
//   transpose_kernel: uT(b,s,w,h) from u; ewT(b,d,w,h) from ew dirs 2,3.
//     -> every direction's sweep streams u and w CONTIGUOUSLY along scan axis.
//   sweep_trans: 8192 tasks (4 dirs x 2048 lines), 21 lanes/task (lane=label),
//     3 tasks per 64-thread wave. float4 group loads (1 per 4 steps) with
//     next-group prefetch. Per-step all-to-all of 21 L values via padded LDS
//     row (wave-synchronous, no s_barrier).
//     dir0 plain-stores L into out (standard layout, contiguous per lane);
//     dirs 1-3 store L into l1/l2/l3 in uniform combine-friendly layout
//     idx = ((b*512+h)*512+w)*24 + s   (pad 24 => 96 B/pixel, 16 B aligned).
//   combine_kernel: out += l1+l2+l3 - 3u; l reads as 6 aligned float4 each.
// Path B fallback (small ws): 4 sequential no-scratch kernels (dir0 store,
//   dirs 1-3 prefetched RMW). Correctness-only.

#define DLBL 21
#define SP 512
#define NB 4
#define SPSP ((long)SP * SP)
#define NELEM ((long)NB * DLBL * SP * SP)   // 22,020,096 floats
#define LPAD 24
#define LSTRIDE ((long)LPAD * NB * SPSP)    // floats per l buffer
#define BIGF 1e30f

// ---------------- transpose: 512x512 planes, 32x32 tiles ----------------
__global__ __launch_bounds__(256)
void transpose_kernel(const float* __restrict__ u, const float* __restrict__ ew,
                      float* __restrict__ uT, float* __restrict__ ewT)
{
    __shared__ float tile[32][33];
    const int plane = blockIdx.z;
    const float* src;
    float* dst;
    if (plane < NB * DLBL) {
        src = u  + (long)plane * SPSP;
        dst = uT + (long)plane * SPSP;
    } else {
        const int q = plane - NB * DLBL;       // 0..7
        const int b = q >> 1, d = 2 + (q & 1);
        src = ew  + (long)(b * 4 + d) * SPSP;
        dst = ewT + (long)q * SPSP;
    }
    const int x0 = blockIdx.x * 32, y0 = blockIdx.y * 32;
    const int tx = threadIdx.x & 31, ty = threadIdx.x >> 5;  // 32 x 8
#pragma unroll
    for (int j = 0; j < 4; ++j)
        tile[ty + 8 * j][tx] = src[(long)(y0 + ty + 8 * j) * SP + (x0 + tx)];
    __syncthreads();
#pragma unroll
    for (int j = 0; j < 4; ++j)
        dst[(long)(x0 + ty + 8 * j) * SP + (y0 + tx)] = tile[tx][ty + 8 * j];
}

// ---------------- main sweep (Path A) ----------------
__global__ __launch_bounds__(64)
void sweep_trans(const float* __restrict__ unary, const float* __restrict__ ew,
                 const float* __restrict__ Vmat,
                 const float* __restrict__ uT, const float* __restrict__ ewT,
                 float* __restrict__ out,
                 float* __restrict__ l1, float* __restrict__ l2,
                 float* __restrict__ l3)
{
    __shared__ float xch[4][24];
    const int lane = threadIdx.x;
    const int g    = lane / DLBL;              // 0..2 (3 = idle lane 63)
    const int s    = lane - g * DLBL;
    int taskId = blockIdx.x * 3 + (g < 3 ? g : 0);
    const bool valid = (g < 3) && (taskId < 8192);
    if (taskId >= 8192) taskId = 8191;

    const int dir  = taskId >> 11;
    const int line = taskId & 2047;
    const int b    = line >> 9;
    const int p    = line & (SP - 1);          // h for axis 0, w for axis 1
    const int axis = dir >> 1;
    const int rev  = dir & 1;

    float Vc[DLBL];
#pragma unroll
    for (int j = 0; j < DLBL; ++j) Vc[j] = Vmat[j * DLBL + s];

    // contiguous scan streams for all directions
    const float* ub = (axis ? uT : unary) + (long)(b * DLBL + s) * SPSP + (long)p * SP;
    const float* wb = axis ? (ewT + ((long)(b * 2 + rev)) * SPSP + (long)p * SP)
                           : (ew  + ((long)(b * 4 + dir)) * SPSP + (long)p * SP);
    float* sb; long sstep;
    if (dir == 0)      { sb = out + (long)(b * DLBL + s) * SPSP + (long)p * SP; sstep = 1; }
    else if (dir == 1) { sb = l1 + ((long)(b * SP + p) * SP) * LPAD + s; sstep = LPAD; }
    else {
        float* lx = (dir == 2) ? l2 : l3;
        sb = lx + (long)b * SPSP * LPAD + (long)p * LPAD + s;            // h = t
        sstep = (long)SP * LPAD;
    }

    const int dstep = rev ? -1 : 1;
    int tg = rev ? (SP / 4 - 1) : 0;
    const float4* ub4 = (const float4*)ub;
    const float4* wb4 = (const float4*)wb;
    float4 uv = ub4[tg], wv = wb4[tg];
    float cur = 0.0f;

    for (int gi = 0; gi < SP / 4; ++gi) {
        const int tgn = (gi + 1 < SP / 4) ? tg + dstep : tg;
        const float4 uvN = ub4[tgn];           // prefetch next group (off-chain)
        const float4 wvN = wb4[tgn];
        const float ua[4] = {uv.x, uv.y, uv.z, uv.w};
        const float wa[4] = {wv.x, wv.y, wv.z, wv.w};
#pragma unroll
        for (int j = 0; j < 4; ++j) {
            const float u_c = rev ? ua[3 - j] : ua[j];
            const float w_c = rev ? wa[3 - j] : wa[j];
            const int   t   = tg * 4 + (rev ? 3 - j : j);
            if (gi == 0 && j == 0) {
                cur = u_c;                     // border: L = u
            } else {
                xch[g][s] = cur;
                __builtin_amdgcn_wave_barrier();
                float Lp[24];
#pragma unroll
                for (int q = 0; q < 6; ++q)
                    ((float4*)Lp)[q] = ((const float4*)(&xch[g][0]))[q];
                __builtin_amdgcn_wave_barrier();

                float c[DLBL];
#pragma unroll
                for (int jj = 0; jj < DLBL; ++jj) c[jj] = fmaf(w_c, Vc[jj], Lp[jj]);
                float m7[7];
#pragma unroll
                for (int k = 0; k < 7; ++k)
                    m7[k] = fminf(fminf(c[3 * k], c[3 * k + 1]), c[3 * k + 2]);
                const float ma = fminf(fminf(m7[0], m7[1]), m7[2]);
                const float mb = fminf(fminf(m7[3], m7[4]), m7[5]);
                cur = u_c + fminf(fminf(ma, mb), m7[6]);
            }
            if (valid) sb[(long)t * sstep] = cur;
        }
        uv = uvN; wv = wvN; tg = tgn;
    }
}

// ---------------- combine (Path A) ----------------
__global__ __launch_bounds__(256)
void combine_kernel(const float* __restrict__ u,
                    const float* __restrict__ l1, const float* __restrict__ l2,
                    const float* __restrict__ l3, float* __restrict__ out)
{
    const long pix = (long)blockIdx.x * 256 + threadIdx.x;  // (b*SP+h)*SP+w
    const int  b   = (int)(pix >> 18);
    const long hw  = pix & (SPSP - 1);
    float a1[24], a2[24], a3[24];
    const float4* p1 = (const float4*)(l1 + pix * LPAD);
    const float4* p2 = (const float4*)(l2 + pix * LPAD);
    const float4* p3 = (const float4*)(l3 + pix * LPAD);
#pragma unroll
    for (int q = 0; q < 6; ++q) {
        ((float4*)a1)[q] = p1[q];
        ((float4*)a2)[q] = p2[q];
        ((float4*)a3)[q] = p3[q];
    }
    const long ubase = (long)b * DLBL * SPSP + hw;
#pragma unroll 7
    for (int s = 0; s < DLBL; ++s) {
        const long uo = ubase + (long)s * SPSP;
        out[uo] = out[uo] + a1[s] + a2[s] + a3[s] - 3.0f * u[uo];
    }
}

// ---------------- fallback (Path B): no-scratch sequential sweeps ----------------
// MODE 1: dir0 store L to out; MODE 2: out += L - u (task owns its elements).
template<int MODE>
__global__ __launch_bounds__(64)
void sweep_fb(const float* __restrict__ unary, const float* __restrict__ ew,
              const float* __restrict__ Vmat, float* __restrict__ out,
              int taskBase)
{
    __shared__ float xch[4][24];
    const int lane = threadIdx.x;
    const int g    = lane / DLBL;
    const int s    = lane - g * DLBL;
    int local = blockIdx.x * 3 + (g < 3 ? g : 0);
    const bool valid = (g < 3) && (local < 2048);
    if (local >= 2048) local = 2047;
    const int taskId = taskBase + local;
    const int dir  = taskId >> 11;
    const int line = taskId & 2047;
    const int b = line >> 9, p = line & (SP - 1);
    const int axis = dir >> 1, rev = dir & 1;

    float Vc[DLBL];
#pragma unroll
    for (int j = 0; j < DLBL; ++j) Vc[j] = Vmat[j * DLBL + s];

    const long ustep = axis ? SP : 1;
    const long ubase = (long)(b * DLBL + s) * SPSP + (axis ? (long)p : (long)p * SP);
    const long wbase = (long)(b * 4 + dir) * SPSP + (axis ? (long)p : (long)p * SP);
    const long uoff  = rev ? -ustep : ustep;
    const long ust   = rev ? (long)(SP - 1) * ustep : 0;

    const float* up = unary + ubase + ust;
    const float* wp = ew    + wbase + ust;
    float*       op = out   + ubase + ust;

    float cur = up[0];
    if (valid && MODE == 1) *op = cur;

    float ub0 = up[uoff], ub1 = up[2*uoff], ub2 = up[3*uoff], ub3 = up[4*uoff];
    float wb0 = wp[uoff], wb1 = wp[2*uoff], wb2 = wp[3*uoff], wb3 = wp[4*uoff];
    float ob0 = 0, ob1 = 0, ob2 = 0, ob3 = 0;
    if (MODE == 2) { ob0 = op[uoff]; ob1 = op[2*uoff]; ob2 = op[3*uoff]; ob3 = op[4*uoff]; }
    const float* upf = up + 4 * uoff;
    const float* wpf = wp + 4 * uoff;
    const float* opf = op + 4 * uoff;

    for (int t = 1; t < SP; ++t) {
        const float u_c = ub0, w_c = wb0, o_c = ob0;
        ub0 = ub1; ub1 = ub2; ub2 = ub3;
        wb0 = wb1; wb1 = wb2; wb2 = wb3;
        if (MODE == 2) { ob0 = ob1; ob1 = ob2; ob2 = ob3; }
        const bool adv = (t + 4) < SP;
        upf += adv ? uoff : 0; wpf += adv ? uoff : 0;
        ub3 = *upf; wb3 = *wpf;
        if (MODE == 2) { opf += adv ? uoff : 0; ob3 = *opf; }

        xch[g][s] = cur;
        __builtin_amdgcn_wave_barrier();
        float Lp[24];
#pragma unroll
        for (int q = 0; q < 6; ++q)
            ((float4*)Lp)[q] = ((const float4*)(&xch[g][0]))[q];
        __builtin_amdgcn_wave_barrier();

        float c[DLBL];
#pragma unroll
        for (int j = 0; j < DLBL; ++j) c[j] = fmaf(w_c, Vc[j], Lp[j]);
        float m7[7];
#pragma unroll
        for (int k = 0; k < 7; ++k)
            m7[k] = fminf(fminf(c[3*k], c[3*k+1]), c[3*k+2]);
        const float ma = fminf(fminf(m7[0], m7[1]), m7[2]);
        const float mb = fminf(fminf(m7[3], m7[4]), m7[5]);
        cur = u_c + fminf(fminf(ma, mb), m7[6]);

        op += uoff;
        if (valid) *op = (MODE == 2) ? (o_c + cur - u_c) : cur;
    }
}

extern "C" void kernel_launch(void* const* d_in, const int* in_sizes, int n_in,
                              void* d_out, int out_size, void* d_ws, size_t ws_size,
                              hipStream_t stream) {
    const float* unary = (const float*)d_in[0];   // (4,1,21,512,512) f32
    const float* ew    = (const float*)d_in[1];   // (4,4,512,512)   f32
    const float* Vmat  = (const float*)d_in[2];   // (21,21)         f32
    float* o = (float*)d_out;

    const long uT_f  = NELEM;
    const long ewT_f = 8 * SPSP;
    const size_t need = (size_t)(uT_f + ewT_f + 3 * LSTRIDE) * sizeof(float);

    if (ws_size >= need) {
        float* uT  = (float*)d_ws;
        float* ewT = uT + uT_f;
        float* l1  = ewT + ewT_f;
        float* l2  = l1 + LSTRIDE;
        float* l3  = l2 + LSTRIDE;
        dim3 tg(16, 16, NB * DLBL + 8);
        transpose_kernel<<<tg, 256, 0, stream>>>(unary, ew, uT, ewT);
        const int grid = (8192 + 2) / 3;          // 2731
        sweep_trans<<<grid, 64, 0, stream>>>(unary, ew, Vmat, uT, ewT,
                                             o, l1, l2, l3);
        combine_kernel<<<(int)(NB * SPSP / 256), 256, 0, stream>>>(
            unary, l1, l2, l3, o);
    } else {
        const int grid = (2048 + 2) / 3;          // 683
        sweep_fb<1><<<grid, 64, 0, stream>>>(unary, ew, Vmat, o, 0);
        for (int d = 1; d < 4; ++d)
            sweep_fb<2><<<grid, 64, 0, stream>>>(unary, ew, Vmat, o, d * 2048);
    }
}

// Round 5
// 915.860 us; speedup vs baseline: 1.7865x; 1.7865x over previous
//
#include <hip/hip_runtime.h>

// SGM min-sum message passing, 4 directions, dense 21x21 label context.
// out = sum_d L_d - 3u.
//
// Path A (ws >= 4*NELEM floats = 352,321,536 B -- the size R3 proved present):
//   transpose_kernel: uT[b][s][w][h] from u  (88 MB of ws).
//   sweep_trans: 8192 tasks (4 dirs x 2048 lines), 21 lanes/task (lane=label),
//     3 tasks per 64-thread wave. u streams contiguously for ALL dirs
//     (unary for horizontal, uT for vertical), float4 per 4-step group with
//     next-group prefetch; w loaded as 4 scalar prefetches per group
//     (stride 1 horiz / 512 vert, task-uniform -> 1 line/step, off-chain).
//     Per-step all-to-all of 21 L values via padded LDS row
//     (wave-synchronous, no s_barrier).
//     dir0 stores L into out (standard layout, lane-sequential);
//     dirs 1-3 store L into l1/l2/l3, ALL pixel-major:
//        idx = ((b*512 + h)*512 + w)*21 + s
//     so every task-step writes 21 consecutive floats and combine reads all
//     three buffers with contiguous 84 B per-thread chunks.
//   combine_kernel: out += l1 + l2 + l3 - 3u  (coalesced u/out, dense l).
// Path B fallback (small ws): R4's 4 sequential no-scratch kernels.

#define DLBL 21
#define SP 512
#define NB 4
#define SPSP ((long)SP * SP)
#define NELEM ((long)NB * DLBL * SP * SP)   // 22,020,096 floats
#define BIGF 1e30f

// ---------------- transpose: u planes only, 32x32 tiles ----------------
__global__ __launch_bounds__(256)
void transpose_kernel(const float* __restrict__ u, float* __restrict__ uT)
{
    __shared__ float tile[32][33];
    const int plane = blockIdx.z;                  // 0..83  (b*21+s)
    const float* src = u  + (long)plane * SPSP;
    float*       dst = uT + (long)plane * SPSP;
    const int x0 = blockIdx.x * 32, y0 = blockIdx.y * 32;
    const int tx = threadIdx.x & 31, ty = threadIdx.x >> 5;  // 32 x 8
#pragma unroll
    for (int j = 0; j < 4; ++j)
        tile[ty + 8 * j][tx] = src[(long)(y0 + ty + 8 * j) * SP + (x0 + tx)];
    __syncthreads();
#pragma unroll
    for (int j = 0; j < 4; ++j)
        dst[(long)(x0 + ty + 8 * j) * SP + (y0 + tx)] = tile[tx][ty + 8 * j];
}

// ---------------- main sweep (Path A) ----------------
__global__ __launch_bounds__(64)
void sweep_trans(const float* __restrict__ unary, const float* __restrict__ ew,
                 const float* __restrict__ Vmat, const float* __restrict__ uT,
                 float* __restrict__ out,
                 float* __restrict__ l1, float* __restrict__ l2,
                 float* __restrict__ l3)
{
    __shared__ float xch[4][24];
    const int lane = threadIdx.x;
    const int g    = lane / DLBL;              // 0..2 (3 = idle lane 63)
    const int s    = lane - g * DLBL;
    int taskId = blockIdx.x * 3 + (g < 3 ? g : 0);
    const bool valid = (g < 3) && (taskId < 8192);
    if (taskId >= 8192) taskId = 8191;

    const int dir  = taskId >> 11;
    const int line = taskId & 2047;
    const int b    = line >> 9;
    const int p    = line & (SP - 1);          // h for axis 0, w for axis 1
    const int axis = dir >> 1;
    const int rev  = dir & 1;

    float Vc[DLBL];
#pragma unroll
    for (int j = 0; j < DLBL; ++j) Vc[j] = Vmat[j * DLBL + s];

    // u stream: contiguous along scan axis for every direction
    const float* ub = (axis ? uT : unary) + (long)(b * DLBL + s) * SPSP + (long)p * SP;
    // w stream: task-uniform; stride 1 (horiz) or 512 (vert)
    const long  wstride = axis ? SP : 1;
    const float* wb = ew + (long)(b * 4 + dir) * SPSP + (axis ? (long)p : (long)p * SP);

    // store stream
    float* sb; long sstep;
    if (dir == 0) {
        sb = out + (long)(b * DLBL + s) * SPSP + (long)p * SP;          sstep = 1;
    } else if (dir == 1) {
        sb = l1 + ((long)b * SPSP + (long)p * SP) * DLBL + s;           sstep = DLBL;
    } else {
        float* lx = (dir == 2) ? l2 : l3;
        sb = lx + ((long)b * SPSP + (long)p) * DLBL + s;                sstep = (long)SP * DLBL;
    }

    const int dstep = rev ? -1 : 1;
    int tg = rev ? (SP / 4 - 1) : 0;
    const float4* ub4 = (const float4*)ub;
    float4 uv = ub4[tg];
    float wv[4];
#pragma unroll
    for (int k = 0; k < 4; ++k) wv[k] = wb[(long)(tg * 4 + k) * wstride];
    float cur = 0.0f;

    for (int gi = 0; gi < SP / 4; ++gi) {
        const int tgn = (gi + 1 < SP / 4) ? tg + dstep : tg;
        const float4 uvN = ub4[tgn];                    // prefetch next group
        float wvN[4];
#pragma unroll
        for (int k = 0; k < 4; ++k) wvN[k] = wb[(long)(tgn * 4 + k) * wstride];
        const float ua[4] = {uv.x, uv.y, uv.z, uv.w};
#pragma unroll
        for (int j = 0; j < 4; ++j) {
            const int   jc  = rev ? 3 - j : j;
            const float u_c = ua[jc];
            const float w_c = wv[jc];
            const int   t   = tg * 4 + jc;
            if (gi == 0 && j == 0) {
                cur = u_c;                              // border: L = u
            } else {
                xch[g][s] = cur;
                __builtin_amdgcn_wave_barrier();
                float Lp[24];
#pragma unroll
                for (int q = 0; q < 6; ++q)
                    ((float4*)Lp)[q] = ((const float4*)(&xch[g][0]))[q];
                __builtin_amdgcn_wave_barrier();

                float c[DLBL];
#pragma unroll
                for (int jj = 0; jj < DLBL; ++jj) c[jj] = fmaf(w_c, Vc[jj], Lp[jj]);
                float m7[7];
#pragma unroll
                for (int k = 0; k < 7; ++k)
                    m7[k] = fminf(fminf(c[3 * k], c[3 * k + 1]), c[3 * k + 2]);
                const float ma = fminf(fminf(m7[0], m7[1]), m7[2]);
                const float mb = fminf(fminf(m7[3], m7[4]), m7[5]);
                cur = u_c + fminf(fminf(ma, mb), m7[6]);
            }
            if (valid) sb[(long)t * sstep] = cur;
        }
        uv = uvN;
#pragma unroll
        for (int k = 0; k < 4; ++k) wv[k] = wvN[k];
        tg = tgn;
    }
}

// ---------------- combine (Path A) ----------------
__global__ __launch_bounds__(256)
void combine_kernel(const float* __restrict__ u,
                    const float* __restrict__ l1, const float* __restrict__ l2,
                    const float* __restrict__ l3, float* __restrict__ out)
{
    const long pix = (long)blockIdx.x * 256 + threadIdx.x;  // (b*SP+h)*SP+w
    const int  b   = (int)(pix >> 18);
    const long hw  = pix & (SPSP - 1);
    const float* p1 = l1 + pix * DLBL;
    const float* p2 = l2 + pix * DLBL;
    const float* p3 = l3 + pix * DLBL;
    const long ubase = (long)b * DLBL * SPSP + hw;
#pragma unroll 7
    for (int s = 0; s < DLBL; ++s) {
        const long uo = ubase + (long)s * SPSP;
        out[uo] = out[uo] + p1[s] + p2[s] + p3[s] - 3.0f * u[uo];
    }
}

// ---------------- fallback (Path B): no-scratch sequential sweeps ----------------
template<int MODE>   // 1: dir0 store L to out; 2: out += L - u
__global__ __launch_bounds__(64)
void sweep_fb(const float* __restrict__ unary, const float* __restrict__ ew,
              const float* __restrict__ Vmat, float* __restrict__ out,
              int taskBase)
{
    __shared__ float xch[4][24];
    const int lane = threadIdx.x;
    const int g    = lane / DLBL;
    const int s    = lane - g * DLBL;
    int local = blockIdx.x * 3 + (g < 3 ? g : 0);
    const bool valid = (g < 3) && (local < 2048);
    if (local >= 2048) local = 2047;
    const int taskId = taskBase + local;
    const int dir  = taskId >> 11;
    const int line = taskId & 2047;
    const int b = line >> 9, p = line & (SP - 1);
    const int axis = dir >> 1, rev = dir & 1;

    float Vc[DLBL];
#pragma unroll
    for (int j = 0; j < DLBL; ++j) Vc[j] = Vmat[j * DLBL + s];

    const long ustep = axis ? SP : 1;
    const long ubase = (long)(b * DLBL + s) * SPSP + (axis ? (long)p : (long)p * SP);
    const long wbase = (long)(b * 4 + dir) * SPSP + (axis ? (long)p : (long)p * SP);
    const long uoff  = rev ? -ustep : ustep;
    const long ust   = rev ? (long)(SP - 1) * ustep : 0;

    const float* up = unary + ubase + ust;
    const float* wp = ew    + wbase + ust;
    float*       op = out   + ubase + ust;

    float cur = up[0];
    if (valid && MODE == 1) *op = cur;

    float ub0 = up[uoff], ub1 = up[2*uoff], ub2 = up[3*uoff], ub3 = up[4*uoff];
    float wb0 = wp[uoff], wb1 = wp[2*uoff], wb2 = wp[3*uoff], wb3 = wp[4*uoff];
    float ob0 = 0, ob1 = 0, ob2 = 0, ob3 = 0;
    if (MODE == 2) { ob0 = op[uoff]; ob1 = op[2*uoff]; ob2 = op[3*uoff]; ob3 = op[4*uoff]; }
    const float* upf = up + 4 * uoff;
    const float* wpf = wp + 4 * uoff;
    const float* opf = op + 4 * uoff;

    for (int t = 1; t < SP; ++t) {
        const float u_c = ub0, w_c = wb0, o_c = ob0;
        ub0 = ub1; ub1 = ub2; ub2 = ub3;
        wb0 = wb1; wb1 = wb2; wb2 = wb3;
        if (MODE == 2) { ob0 = ob1; ob1 = ob2; ob2 = ob3; }
        const bool adv = (t + 4) < SP;
        upf += adv ? uoff : 0; wpf += adv ? uoff : 0;
        ub3 = *upf; wb3 = *wpf;
        if (MODE == 2) { opf += adv ? uoff : 0; ob3 = *opf; }

        xch[g][s] = cur;
        __builtin_amdgcn_wave_barrier();
        float Lp[24];
#pragma unroll
        for (int q = 0; q < 6; ++q)
            ((float4*)Lp)[q] = ((const float4*)(&xch[g][0]))[q];
        __builtin_amdgcn_wave_barrier();

        float c[DLBL];
#pragma unroll
        for (int j = 0; j < DLBL; ++j) c[j] = fmaf(w_c, Vc[j], Lp[j]);
        float m7[7];
#pragma unroll
        for (int k = 0; k < 7; ++k)
            m7[k] = fminf(fminf(c[3*k], c[3*k+1]), c[3*k+2]);
        const float ma = fminf(fminf(m7[0], m7[1]), m7[2]);
        const float mb = fminf(fminf(m7[3], m7[4]), m7[5]);
        cur = u_c + fminf(fminf(ma, mb), m7[6]);

        op += uoff;
        if (valid) *op = (MODE == 2) ? (o_c + cur - u_c) : cur;
    }
}

extern "C" void kernel_launch(void* const* d_in, const int* in_sizes, int n_in,
                              void* d_out, int out_size, void* d_ws, size_t ws_size,
                              hipStream_t stream) {
    const float* unary = (const float*)d_in[0];   // (4,1,21,512,512) f32
    const float* ew    = (const float*)d_in[1];   // (4,4,512,512)   f32
    const float* Vmat  = (const float*)d_in[2];   // (21,21)         f32
    float* o = (float*)d_out;

    const size_t need = (size_t)(4 * NELEM) * sizeof(float);  // 352,321,536 B

    if (ws_size >= need) {
        float* uT = (float*)d_ws;
        float* l1 = uT + NELEM;
        float* l2 = l1 + NELEM;
        float* l3 = l2 + NELEM;
        dim3 tg(16, 16, NB * DLBL);
        transpose_kernel<<<tg, 256, 0, stream>>>(unary, uT);
        const int grid = (8192 + 2) / 3;          // 2731
        sweep_trans<<<grid, 64, 0, stream>>>(unary, ew, Vmat, uT,
                                             o, l1, l2, l3);
        combine_kernel<<<(int)(NB * SPSP / 256), 256, 0, stream>>>(
            unary, l1, l2, l3, o);
    } else {
        const int grid = (2048 + 2) / 3;          // 683
        sweep_fb<1><<<grid, 64, 0, stream>>>(unary, ew, Vmat, o, 0);
        for (int d = 1; d < 4; ++d)
            sweep_fb<2><<<grid, 64, 0, stream>>>(unary, ew, Vmat, o, d * 2048);
    }
}